// Round 21
// baseline (87.181 us; speedup 1.0000x reference)
//
#include <hip/hip_runtime.h>
#include <cmath>

typedef __attribute__((ext_vector_type(8))) short bf16x8;
typedef __attribute__((ext_vector_type(4))) float f32x4;
typedef unsigned short u16;
typedef unsigned int u32;

#define OUT1OFF 33554432   // 8*128*128*256

__device__ __forceinline__ u16 f2bf(float f) {
  union { float f; u32 u; } v; v.f = f;
  u32 r = v.u + 0x7fffu + ((v.u >> 16) & 1u);  // RNE
  return (u16)(r >> 16);
}

__device__ __forceinline__ float frcp(float x) {
  float r;
  asm("v_rcp_f32 %0, %1" : "=v"(r) : "v"(x));
  return r;
}

__device__ __forceinline__ u32 cvt_pk_bf16(float lo, float hi) {
  u32 r;
  asm("v_cvt_pk_bf16_f32 %0, %1, %2" : "=v"(r) : "v"(lo), "v"(hi));
  return r;
}

// tanh-form gelu: x * sigmoid(2c(x+0.044715x^3)), max dev from exact ~6e-4
__device__ __forceinline__ float gelu_t(float x) {
  const float x2 = x * x;
  const float z = 1.5957691216057308f * x * fmaf(0.044715f, x2, 1.0f);
  return x * frcp(1.0f + __expf(-z));
}

// ---------------- k1: U = x@Wtop, Y = x@Wbot + b ; W1F fragment-major bf16 ----------------
__global__ __launch_bounds__(256) void k1_prep(
    const float* __restrict__ x, const float* __restrict__ Wn2e,
    const float* __restrict__ bn2e, const float* __restrict__ W1,
    float* __restrict__ Uw, float* __restrict__ Yw, u16* __restrict__ W1F)
{
  __shared__ float xl[4][256];
  const int t = threadIdx.x;
  const int blk = blockIdx.x;      // 0..255, 4 node-rows each
  const int r0 = blk * 4;
  {
    const int rr = t >> 6, c4 = (t & 63) * 4;
    *(float4*)&xl[rr][c4] = *(const float4*)&x[(r0 + rr) * 256 + c4];
  }
  __syncthreads();
  const int c = t;
  float u0=0.f,u1=0.f,u2=0.f,u3=0.f,y0=0.f,y1=0.f,y2=0.f,y3=0.f;
  #pragma unroll 4
  for (int k = 0; k < 256; ++k) {
    const float wt = Wn2e[k * 256 + c];
    const float wb = Wn2e[(k + 256) * 256 + c];
    const float a0 = xl[0][k], a1 = xl[1][k], a2 = xl[2][k], a3 = xl[3][k];
    u0 = fmaf(a0, wt, u0); u1 = fmaf(a1, wt, u1);
    u2 = fmaf(a2, wt, u2); u3 = fmaf(a3, wt, u3);
    y0 = fmaf(a0, wb, y0); y1 = fmaf(a1, wb, y1);
    y2 = fmaf(a2, wb, y2); y3 = fmaf(a3, wb, y3);
  }
  const float bb = bn2e[c];
  Uw[(r0+0)*256+c]=u0; Uw[(r0+1)*256+c]=u1; Uw[(r0+2)*256+c]=u2; Uw[(r0+3)*256+c]=u3;
  Yw[(r0+0)*256+c]=y0+bb; Yw[(r0+1)*256+c]=y1+bb; Yw[(r0+2)*256+c]=y2+bb; Yw[(r0+3)*256+c]=y3+bb;
  // W1F: fragment-major. e = ((nt*8+ks)*64 + l)*8 + d holds W1[kg][n],
  // n = nt*16 + (l&15), kg = ks*32 + ((l>>4)&3)*8 + d.
  if (blk < 64) {
    #pragma unroll
    for (int q = 0; q < 2; ++q) {
      const int e = (blk * 256 + t) * 2 + q;
      const int d = e & 7, lf = (e >> 3) & 63, ks = (e >> 9) & 7, nt = (e >> 12) & 7;
      const int n = nt * 16 + (lf & 15);
      const int kg = ks * 32 + ((lf >> 4) & 3) * 8 + d;
      W1F[e] = f2bf(W1[kg * 128 + n]);
    }
  }
}

// ---- k2: R19 max-occupancy structure, PLAIN stores (A/B vs R19's NT stores).
// 32-row tiles, 16 KB LDS, 4 waves, VGPR<=64 -> 8 blocks/CU = 32 waves/CU. ----
__global__ __launch_bounds__(256, 8) void k2_fused(
    const float* __restrict__ Uw, const float* __restrict__ Yw,
    const u16* __restrict__ W1F, const float* __restrict__ b1,
    const float* __restrict__ W2, const float* __restrict__ b2p,
    const float* __restrict__ E, float* __restrict__ out)
{
  __shared__ u16 ezLds[32 * 256];      // 16 KB, swizzled: idx ^= (jj&7)<<3
  __shared__ float psumBuf[2][32];
  const int t = threadIdx.x;
  const int blk = blockIdx.x;          // pair*4 + quarter
  const int pair = blk >> 2;           // b*128 + i
  const int j0 = (blk & 3) * 32;
  const int b = pair >> 7;
  const int rw = t >> 6;               // wave id 0..3
  const int l = t & 63;
  const int c4 = l * 4;

  const f32x4 uv = *(const f32x4*)&Uw[pair * 256 + c4];
  const int eBase = (pair * 128 + j0) * 256 + c4;   // E/out base (jj=0)
  const int yBase = (b * 128 + j0) * 256 + c4;      // Y base (jj=0)

  // Phase A: 8 rows per wave (jj = it*4+rw), coalesced 1KB row ops.
  #pragma unroll 2
  for (int it = 0; it < 8; ++it) {
    const int jj = it * 4 + rw;
    const f32x4 yv = *(const f32x4*)&Yw[yBase + jj * 256];
    const f32x4 ev = *(const f32x4*)&E[eBase + jj * 256];
    const float ez0 = gelu_t(uv.x + yv.x);
    const float ez1 = gelu_t(uv.y + yv.y);
    const float ez2 = gelu_t(uv.z + yv.z);
    const float ez3 = gelu_t(uv.w + yv.w);
    uint2 pk;
    pk.x = cvt_pk_bf16(ez0, ez1);
    pk.y = cvt_pk_bf16(ez2, ez3);
    const int idx = (jj * 256 + c4) ^ ((jj & 7) << 3);
    *(uint2*)&ezLds[idx] = pk;
    // out0 = ez + (1 - 0.5*exp(sigmoid(ez)))*E  (curvature term <=1.8e-4, dropped)
    f32x4 o;
    o.x = ez0 + (1.f - 0.5f * __expf(frcp(1.f + __expf(-ez0)))) * ev.x;
    o.y = ez1 + (1.f - 0.5f * __expf(frcp(1.f + __expf(-ez1)))) * ev.y;
    o.z = ez2 + (1.f - 0.5f * __expf(frcp(1.f + __expf(-ez2)))) * ev.z;
    o.w = ez3 + (1.f - 0.5f * __expf(frcp(1.f + __expf(-ez3)))) * ev.w;
    *(f32x4*)&out[eBase + jj * 256] = o;        // PLAIN store (R19 used NT)
  }
  __syncthreads();

  // Phase B: wave w -> rows (w>>1)*16..+15, cols (w&1)*64..+63.
  const int l15 = l & 15, lh = l >> 4;
  const int mrow = (rw >> 1) * 16;
  const int nh = rw & 1;               // N-half
  f32x4 acc[4];
  #pragma unroll
  for (int nt = 0; nt < 4; ++nt) acc[nt] = (f32x4){0.f, 0.f, 0.f, 0.f};
  #pragma unroll
  for (int ks = 0; ks < 8; ++ks) {
    const int k = ks * 32 + lh * 8;
    const int aidx = ((mrow + l15) * 256 + k) ^ ((l15 & 7) << 3);
    const bf16x8 a = *(const bf16x8*)&ezLds[aidx];
    #pragma unroll
    for (int nt = 0; nt < 4; ++nt) {
      const int ntg = nh * 4 + nt;
      const bf16x8 bv = *(const bf16x8*)&W1F[(((ntg << 3) | ks) * 64 + l) * 8];
      acc[nt] = __builtin_amdgcn_mfma_f32_16x16x32_bf16(a, bv, acc[nt], 0, 0, 0);
    }
  }
  // GEMM3 partials over this wave's 64 cols
  float ps0=0.f, ps1=0.f, ps2=0.f, ps3=0.f;
  #pragma unroll
  for (int nt = 0; nt < 4; ++nt) {
    const int col = nh * 64 + nt * 16 + l15;
    const float bv = b1[col], wvv = W2[col];
    ps0 += fmaxf(acc[nt][0] + bv, 0.f) * wvv;
    ps1 += fmaxf(acc[nt][1] + bv, 0.f) * wvv;
    ps2 += fmaxf(acc[nt][2] + bv, 0.f) * wvv;
    ps3 += fmaxf(acc[nt][3] + bv, 0.f) * wvv;
  }
  #pragma unroll
  for (int m = 1; m < 16; m <<= 1) {
    ps0 += __shfl_xor(ps0, m, 64);
    ps1 += __shfl_xor(ps1, m, 64);
    ps2 += __shfl_xor(ps2, m, 64);
    ps3 += __shfl_xor(ps3, m, 64);
  }
  // lane l<16 picks e2v-partial of row (mrow+l): reg (l&3) of lanes lh=l>>2
  {
    const int srcLane = ((l15 >> 2) << 4) | l15;
    const float s0 = __shfl(ps0, srcLane, 64);
    const float s1 = __shfl(ps1, srcLane, 64);
    const float s2 = __shfl(ps2, srcLane, 64);
    const float s3 = __shfl(ps3, srcLane, 64);
    const float t01 = (l15 & 1) ? s1 : s0;
    const float t23 = (l15 & 1) ? s3 : s2;
    const float s = (l15 & 2) ? t23 : t01;
    if (l < 16) psumBuf[nh][mrow + l] = s;
  }
  __syncthreads();
  if (t < 32) {
    const float s = fmaxf(psumBuf[0][t] + psumBuf[1][t] + b2p[0], 0.f);
    out[OUT1OFF + pair * 128 + j0 + t] = s;
  }
}

extern "C" void kernel_launch(void* const* d_in, const int* in_sizes, int n_in,
                              void* d_out, int out_size, void* d_ws, size_t ws_size,
                              hipStream_t stream) {
  const float* x    = (const float*)d_in[0];   // [1024, 256]
  const float* E    = (const float*)d_in[1];   // [131072, 256]
  const float* Wn2e = (const float*)d_in[2];   // [512, 256]
  const float* bn2e = (const float*)d_in[3];   // [256]
  const float* W1   = (const float*)d_in[4];   // [256, 128]
  const float* b1   = (const float*)d_in[5];   // [128]
  const float* W2   = (const float*)d_in[6];   // [128]
  const float* b2   = (const float*)d_in[7];   // [1]
  float* out = (float*)d_out;

  float* Uw = (float*)d_ws;                    // [1024, 256] f32
  float* Yw = Uw + 262144;                     // [1024, 256] f32
  u16*  W1F = (u16*)(Yw + 262144);             // [32768] bf16, fragment-major

  hipLaunchKernelGGL(k1_prep, dim3(256), dim3(256), 0, stream,
                     x, Wn2e, bn2e, W1, Uw, Yw, W1F);
  // 4096 blocks x 256 threads: 32-row tiles, 8 blocks/CU target
  hipLaunchKernelGGL(k2_fused, dim3(4096), dim3(256), 0, stream,
                     Uw, Yw, W1F, b1, W2, b2, E, out);
}

// Round 22
// 77.462 us; speedup vs baseline: 1.1255x; 1.1255x over previous
//
#include <hip/hip_runtime.h>
#include <cmath>

typedef __attribute__((ext_vector_type(8))) short bf16x8;
typedef __attribute__((ext_vector_type(4))) float f32x4;
typedef unsigned short u16;
typedef unsigned int u32;

#define OUT1OFF 33554432   // 8*128*128*256

__device__ __forceinline__ u16 f2bf(float f) {
  union { float f; u32 u; } v; v.f = f;
  u32 r = v.u + 0x7fffu + ((v.u >> 16) & 1u);  // RNE
  return (u16)(r >> 16);
}

__device__ __forceinline__ float frcp(float x) {
  float r;
  asm("v_rcp_f32 %0, %1" : "=v"(r) : "v"(x));
  return r;
}

__device__ __forceinline__ float ex2(float x) {  // 2^x, native
  float r;
  asm("v_exp_f32 %0, %1" : "=v"(r) : "v"(x));
  return r;
}

__device__ __forceinline__ u32 cvt_pk_bf16(float lo, float hi) {
  u32 r;
  asm("v_cvt_pk_bf16_f32 %0, %1, %2" : "=v"(r) : "v"(lo), "v"(hi));
  return r;
}

// tanh-form gelu via native exp2 (log2e folded into the constant):
// ez = w / (1 + 2^(-2.3022*w*(1+0.044715*w^2)))
__device__ __forceinline__ float gelu_t(float x) {
  const float x2 = x * x;
  const float z2 = -2.3022077437332706f * x * fmaf(0.044715f, x2, 1.0f);
  return x * frcp(1.0f + ex2(z2));
}

#define LOG2E 1.4426950408889634f

// ---------------- k1: U = x@Wtop, Y = x@Wbot + b ; W1F fragment-major bf16 ----------------
__global__ __launch_bounds__(256) void k1_prep(
    const float* __restrict__ x, const float* __restrict__ Wn2e,
    const float* __restrict__ bn2e, const float* __restrict__ W1,
    float* __restrict__ Uw, float* __restrict__ Yw, u16* __restrict__ W1F)
{
  __shared__ float xl[4][256];
  const int t = threadIdx.x;
  const int blk = blockIdx.x;      // 0..255, 4 node-rows each
  const int r0 = blk * 4;
  {
    const int rr = t >> 6, c4 = (t & 63) * 4;
    *(float4*)&xl[rr][c4] = *(const float4*)&x[(r0 + rr) * 256 + c4];
  }
  __syncthreads();
  const int c = t;
  float u0=0.f,u1=0.f,u2=0.f,u3=0.f,y0=0.f,y1=0.f,y2=0.f,y3=0.f;
  #pragma unroll 4
  for (int k = 0; k < 256; ++k) {
    const float wt = Wn2e[k * 256 + c];
    const float wb = Wn2e[(k + 256) * 256 + c];
    const float a0 = xl[0][k], a1 = xl[1][k], a2 = xl[2][k], a3 = xl[3][k];
    u0 = fmaf(a0, wt, u0); u1 = fmaf(a1, wt, u1);
    u2 = fmaf(a2, wt, u2); u3 = fmaf(a3, wt, u3);
    y0 = fmaf(a0, wb, y0); y1 = fmaf(a1, wb, y1);
    y2 = fmaf(a2, wb, y2); y3 = fmaf(a3, wb, y3);
  }
  const float bb = bn2e[c];
  Uw[(r0+0)*256+c]=u0; Uw[(r0+1)*256+c]=u1; Uw[(r0+2)*256+c]=u2; Uw[(r0+3)*256+c]=u3;
  Yw[(r0+0)*256+c]=y0+bb; Yw[(r0+1)*256+c]=y1+bb; Yw[(r0+2)*256+c]=y2+bb; Yw[(r0+3)*256+c]=y3+bb;
  // W1F: fragment-major. e = ((nt*8+ks)*64 + l)*8 + d holds W1[kg][n],
  // n = nt*16 + (l&15), kg = ks*32 + ((l>>4)&3)*8 + d.
  if (blk < 64) {
    #pragma unroll
    for (int q = 0; q < 2; ++q) {
      const int e = (blk * 256 + t) * 2 + q;
      const int d = e & 7, lf = (e >> 3) & 63, ks = (e >> 9) & 7, nt = (e >> 12) & 7;
      const int n = nt * 16 + (lf & 15);
      const int kg = ks * 32 + ((lf >> 4) & 3) * 8 + d;
      W1F[e] = f2bf(W1[kg * 128 + n]);
    }
  }
}

// ---- k2: R20 structure (32-row tiles, wave-contiguous streams, XCD swizzle,
// NT stores) + FULL unroll Phase A (8 row-loads in flight per wave; VGPR
// budget 64, was using only 28) + exp2-folded transcendentals. ----
__global__ __launch_bounds__(256, 8) void k2_fused(
    const float* __restrict__ Uw, const float* __restrict__ Yw,
    const u16* __restrict__ W1F, const float* __restrict__ b1,
    const float* __restrict__ W2, const float* __restrict__ b2p,
    const float* __restrict__ E, float* __restrict__ out)
{
  __shared__ u16 ezLds[32 * 256];      // 16 KB, swizzled: idx ^= (jj&7)<<3
  __shared__ float psumBuf[2][32];
  const int t = threadIdx.x;
  // XCD swizzle: 4096 blocks, 8 XCDs -> XCD x owns contiguous orig-range [x*512,(x+1)*512)
  const int bid = blockIdx.x;
  const int blk = (bid & 7) * 512 + (bid >> 3);   // bijective (4096 % 8 == 0)
  const int pair = blk >> 2;           // b*128 + i
  const int j0 = (blk & 3) * 32;
  const int b = pair >> 7;
  const int rw = t >> 6;               // wave id 0..3
  const int l = t & 63;
  const int c4 = l * 4;

  const f32x4 uv = *(const f32x4*)&Uw[pair * 256 + c4];
  const int eBase = (pair * 128 + j0) * 256 + c4;   // E/out base (jj=0)
  const int yBase = (b * 128 + j0) * 256 + c4;      // Y base (jj=0)

  // Phase A: 8 CONSECUTIVE rows per wave (jj = rw*8+it), fully unrolled so the
  // scheduler can keep many E/Y loads in flight (VGPR headroom 28->64).
  #pragma unroll
  for (int it = 0; it < 8; ++it) {
    const int jj = rw * 8 + it;
    const f32x4 yv = *(const f32x4*)&Yw[yBase + jj * 256];
    const f32x4 ev = *(const f32x4*)&E[eBase + jj * 256];
    const float ez0 = gelu_t(uv.x + yv.x);
    const float ez1 = gelu_t(uv.y + yv.y);
    const float ez2 = gelu_t(uv.z + yv.z);
    const float ez3 = gelu_t(uv.w + yv.w);
    uint2 pk;
    pk.x = cvt_pk_bf16(ez0, ez1);
    pk.y = cvt_pk_bf16(ez2, ez3);
    const int idx = (jj * 256 + c4) ^ ((jj & 7) << 3);
    *(uint2*)&ezLds[idx] = pk;
    // out0 = ez + (1 - 0.5*exp(sigmoid(ez)))*E  (curvature term <=1.8e-4, dropped)
    f32x4 o;
    {
      const float sg = frcp(1.f + ex2(-LOG2E * ez0));
      o.x = fmaf(fmaf(-0.5f, ex2(LOG2E * sg), 1.f), ev.x, ez0);
    }
    {
      const float sg = frcp(1.f + ex2(-LOG2E * ez1));
      o.y = fmaf(fmaf(-0.5f, ex2(LOG2E * sg), 1.f), ev.y, ez1);
    }
    {
      const float sg = frcp(1.f + ex2(-LOG2E * ez2));
      o.z = fmaf(fmaf(-0.5f, ex2(LOG2E * sg), 1.f), ev.z, ez2);
    }
    {
      const float sg = frcp(1.f + ex2(-LOG2E * ez3));
      o.w = fmaf(fmaf(-0.5f, ex2(LOG2E * sg), 1.f), ev.w, ez3);
    }
    __builtin_nontemporal_store(o, (f32x4*)&out[eBase + jj * 256]);
  }
  __syncthreads();

  // Phase B: wave w -> rows (w>>1)*16..+15, cols (w&1)*64..+63.
  const int l15 = l & 15, lh = l >> 4;
  const int mrow = (rw >> 1) * 16;
  const int nh = rw & 1;               // N-half
  f32x4 acc[4];
  #pragma unroll
  for (int nt = 0; nt < 4; ++nt) acc[nt] = (f32x4){0.f, 0.f, 0.f, 0.f};
  #pragma unroll
  for (int ks = 0; ks < 8; ++ks) {
    const int k = ks * 32 + lh * 8;
    const int aidx = ((mrow + l15) * 256 + k) ^ ((l15 & 7) << 3);
    const bf16x8 a = *(const bf16x8*)&ezLds[aidx];
    #pragma unroll
    for (int nt = 0; nt < 4; ++nt) {
      const int ntg = nh * 4 + nt;
      const bf16x8 bv = *(const bf16x8*)&W1F[(((ntg << 3) | ks) * 64 + l) * 8];
      acc[nt] = __builtin_amdgcn_mfma_f32_16x16x32_bf16(a, bv, acc[nt], 0, 0, 0);
    }
  }
  // GEMM3 partials over this wave's 64 cols
  float ps0=0.f, ps1=0.f, ps2=0.f, ps3=0.f;
  #pragma unroll
  for (int nt = 0; nt < 4; ++nt) {
    const int col = nh * 64 + nt * 16 + l15;
    const float bv = b1[col], wvv = W2[col];
    ps0 += fmaxf(acc[nt][0] + bv, 0.f) * wvv;
    ps1 += fmaxf(acc[nt][1] + bv, 0.f) * wvv;
    ps2 += fmaxf(acc[nt][2] + bv, 0.f) * wvv;
    ps3 += fmaxf(acc[nt][3] + bv, 0.f) * wvv;
  }
  #pragma unroll
  for (int m = 1; m < 16; m <<= 1) {
    ps0 += __shfl_xor(ps0, m, 64);
    ps1 += __shfl_xor(ps1, m, 64);
    ps2 += __shfl_xor(ps2, m, 64);
    ps3 += __shfl_xor(ps3, m, 64);
  }
  // lane l<16 picks e2v-partial of row (mrow+l): reg (l&3) of lanes lh=l>>2
  {
    const int srcLane = ((l15 >> 2) << 4) | l15;
    const float s0 = __shfl(ps0, srcLane, 64);
    const float s1 = __shfl(ps1, srcLane, 64);
    const float s2 = __shfl(ps2, srcLane, 64);
    const float s3 = __shfl(ps3, srcLane, 64);
    const float t01 = (l15 & 1) ? s1 : s0;
    const float t23 = (l15 & 1) ? s3 : s2;
    const float s = (l15 & 2) ? t23 : t01;
    if (l < 16) psumBuf[nh][mrow + l] = s;
  }
  __syncthreads();
  if (t < 32) {
    const float s = fmaxf(psumBuf[0][t] + psumBuf[1][t] + b2p[0], 0.f);
    out[OUT1OFF + pair * 128 + j0 + t] = s;
  }
}

extern "C" void kernel_launch(void* const* d_in, const int* in_sizes, int n_in,
                              void* d_out, int out_size, void* d_ws, size_t ws_size,
                              hipStream_t stream) {
  const float* x    = (const float*)d_in[0];   // [1024, 256]
  const float* E    = (const float*)d_in[1];   // [131072, 256]
  const float* Wn2e = (const float*)d_in[2];   // [512, 256]
  const float* bn2e = (const float*)d_in[3];   // [256]
  const float* W1   = (const float*)d_in[4];   // [256, 128]
  const float* b1   = (const float*)d_in[5];   // [128]
  const float* W2   = (const float*)d_in[6];   // [128]
  const float* b2   = (const float*)d_in[7];   // [1]
  float* out = (float*)d_out;

  float* Uw = (float*)d_ws;                    // [1024, 256] f32
  float* Yw = Uw + 262144;                     // [1024, 256] f32
  u16*  W1F = (u16*)(Yw + 262144);             // [32768] bf16, fragment-major

  hipLaunchKernelGGL(k1_prep, dim3(256), dim3(256), 0, stream,
                     x, Wn2e, bn2e, W1, Uw, Yw, W1F);
  // 4096 blocks x 256 threads: 32-row tiles, wave-contiguous streams, XCD swizzle
  hipLaunchKernelGGL(k2_fused, dim3(4096), dim3(256), 0, stream,
                     Uw, Yw, W1F, b1, W2, b2, E, out);
}

// Round 23
// 75.228 us; speedup vs baseline: 1.1589x; 1.0297x over previous
//
#include <hip/hip_runtime.h>
#include <cmath>

typedef __attribute__((ext_vector_type(8))) short bf16x8;
typedef __attribute__((ext_vector_type(4))) float f32x4;
typedef unsigned short u16;
typedef unsigned int u32;

#define OUT1OFF 33554432   // 8*128*128*256

__device__ __forceinline__ u16 f2bf(float f) {
  union { float f; u32 u; } v; v.f = f;
  u32 r = v.u + 0x7fffu + ((v.u >> 16) & 1u);  // RNE
  return (u16)(r >> 16);
}

__device__ __forceinline__ float frcp(float x) {
  float r;
  asm("v_rcp_f32 %0, %1" : "=v"(r) : "v"(x));
  return r;
}

__device__ __forceinline__ u32 cvt_pk_bf16(float lo, float hi) {
  u32 r;
  asm("v_cvt_pk_bf16_f32 %0, %1, %2" : "=v"(r) : "v"(lo), "v"(hi));
  return r;
}

// tanh-form gelu: x * sigmoid(2c(x+0.044715x^3)), max dev from exact ~6e-4
__device__ __forceinline__ float gelu_t(float x) {
  const float x2 = x * x;
  const float z = 1.5957691216057308f * x * fmaf(0.044715f, x2, 1.0f);
  return x * frcp(1.0f + __expf(-z));
}

// ---------------- k1: U = x@Wtop, Y = x@Wbot + b ; W1F fragment-major bf16 ----------------
__global__ __launch_bounds__(256) void k1_prep(
    const float* __restrict__ x, const float* __restrict__ Wn2e,
    const float* __restrict__ bn2e, const float* __restrict__ W1,
    float* __restrict__ Uw, float* __restrict__ Yw, u16* __restrict__ W1F)
{
  __shared__ float xl[4][256];
  const int t = threadIdx.x;
  const int blk = blockIdx.x;      // 0..255, 4 node-rows each
  const int r0 = blk * 4;
  {
    const int rr = t >> 6, c4 = (t & 63) * 4;
    *(float4*)&xl[rr][c4] = *(const float4*)&x[(r0 + rr) * 256 + c4];
  }
  __syncthreads();
  const int c = t;
  float u0=0.f,u1=0.f,u2=0.f,u3=0.f,y0=0.f,y1=0.f,y2=0.f,y3=0.f;
  #pragma unroll 4
  for (int k = 0; k < 256; ++k) {
    const float wt = Wn2e[k * 256 + c];
    const float wb = Wn2e[(k + 256) * 256 + c];
    const float a0 = xl[0][k], a1 = xl[1][k], a2 = xl[2][k], a3 = xl[3][k];
    u0 = fmaf(a0, wt, u0); u1 = fmaf(a1, wt, u1);
    u2 = fmaf(a2, wt, u2); u3 = fmaf(a3, wt, u3);
    y0 = fmaf(a0, wb, y0); y1 = fmaf(a1, wb, y1);
    y2 = fmaf(a2, wb, y2); y3 = fmaf(a3, wb, y3);
  }
  const float bb = bn2e[c];
  Uw[(r0+0)*256+c]=u0; Uw[(r0+1)*256+c]=u1; Uw[(r0+2)*256+c]=u2; Uw[(r0+3)*256+c]=u3;
  Yw[(r0+0)*256+c]=y0+bb; Yw[(r0+1)*256+c]=y1+bb; Yw[(r0+2)*256+c]=y2+bb; Yw[(r0+3)*256+c]=y3+bb;
  // W1F: fragment-major. e = ((nt*8+ks)*64 + l)*8 + d holds W1[kg][n],
  // n = nt*16 + (l&15), kg = ks*32 + ((l>>4)&3)*8 + d.
  if (blk < 64) {
    #pragma unroll
    for (int q = 0; q < 2; ++q) {
      const int e = (blk * 256 + t) * 2 + q;
      const int d = e & 7, lf = (e >> 3) & 63, ks = (e >> 9) & 7, nt = (e >> 12) & 7;
      const int n = nt * 16 + (lf & 15);
      const int kg = ks * 32 + ((lf >> 4) & 3) * 8 + d;
      W1F[e] = f2bf(W1[kg * 128 + n]);
    }
  }
}

// ---- k2: best-measured variant (R20, 75.35 us). Max-occupancy fused:
// 32-row tiles, 16 KB LDS, 4 waves, VGPR<=64 -> 8 blocks/CU. Wave-contiguous
// streaming (jj = rw*8+it), bijective XCD swizzle, NT stores (R21 A/B: +12us
// if removed). Phase A: gelu -> out0 (k==2) + bf16 swizzled LDS. Phase B:
// per-wave (16row x 64col) GEMM2 quadrant + GEMM3 psum via LDS. ----
__global__ __launch_bounds__(256, 8) void k2_fused(
    const float* __restrict__ Uw, const float* __restrict__ Yw,
    const u16* __restrict__ W1F, const float* __restrict__ b1,
    const float* __restrict__ W2, const float* __restrict__ b2p,
    const float* __restrict__ E, float* __restrict__ out)
{
  __shared__ u16 ezLds[32 * 256];      // 16 KB, swizzled: idx ^= (jj&7)<<3
  __shared__ float psumBuf[2][32];
  const int t = threadIdx.x;
  // XCD swizzle: 4096 blocks, 8 XCDs -> XCD x owns contiguous orig-range [x*512,(x+1)*512)
  const int bid = blockIdx.x;
  const int blk = (bid & 7) * 512 + (bid >> 3);   // bijective (4096 % 8 == 0)
  const int pair = blk >> 2;           // b*128 + i
  const int j0 = (blk & 3) * 32;
  const int b = pair >> 7;
  const int rw = t >> 6;               // wave id 0..3
  const int l = t & 63;
  const int c4 = l * 4;

  const f32x4 uv = *(const f32x4*)&Uw[pair * 256 + c4];
  const int eBase = (pair * 128 + j0) * 256 + c4;   // E/out base (jj=0)
  const int yBase = (b * 128 + j0) * 256 + c4;      // Y base (jj=0)

  // Phase A: 8 CONSECUTIVE rows per wave (jj = rw*8+it), 1KB-sequential streams.
  #pragma unroll 2
  for (int it = 0; it < 8; ++it) {
    const int jj = rw * 8 + it;
    const f32x4 yv = *(const f32x4*)&Yw[yBase + jj * 256];
    const f32x4 ev = *(const f32x4*)&E[eBase + jj * 256];
    const float ez0 = gelu_t(uv.x + yv.x);
    const float ez1 = gelu_t(uv.y + yv.y);
    const float ez2 = gelu_t(uv.z + yv.z);
    const float ez3 = gelu_t(uv.w + yv.w);
    uint2 pk;
    pk.x = cvt_pk_bf16(ez0, ez1);
    pk.y = cvt_pk_bf16(ez2, ez3);
    const int idx = (jj * 256 + c4) ^ ((jj & 7) << 3);
    *(uint2*)&ezLds[idx] = pk;
    // out0 = ez + (1 - 0.5*exp(sigmoid(ez)))*E  (curvature term <=1.8e-4, dropped)
    f32x4 o;
    o.x = ez0 + (1.f - 0.5f * __expf(frcp(1.f + __expf(-ez0)))) * ev.x;
    o.y = ez1 + (1.f - 0.5f * __expf(frcp(1.f + __expf(-ez1)))) * ev.y;
    o.z = ez2 + (1.f - 0.5f * __expf(frcp(1.f + __expf(-ez2)))) * ev.z;
    o.w = ez3 + (1.f - 0.5f * __expf(frcp(1.f + __expf(-ez3)))) * ev.w;
    __builtin_nontemporal_store(o, (f32x4*)&out[eBase + jj * 256]);
  }
  __syncthreads();

  // Phase B: wave w -> rows (w>>1)*16..+15, cols (w&1)*64..+63.
  const int l15 = l & 15, lh = l >> 4;
  const int mrow = (rw >> 1) * 16;
  const int nh = rw & 1;               // N-half
  f32x4 acc[4];
  #pragma unroll
  for (int nt = 0; nt < 4; ++nt) acc[nt] = (f32x4){0.f, 0.f, 0.f, 0.f};
  #pragma unroll
  for (int ks = 0; ks < 8; ++ks) {
    const int k = ks * 32 + lh * 8;
    const int aidx = ((mrow + l15) * 256 + k) ^ ((l15 & 7) << 3);
    const bf16x8 a = *(const bf16x8*)&ezLds[aidx];
    #pragma unroll
    for (int nt = 0; nt < 4; ++nt) {
      const int ntg = nh * 4 + nt;
      const bf16x8 bv = *(const bf16x8*)&W1F[(((ntg << 3) | ks) * 64 + l) * 8];
      acc[nt] = __builtin_amdgcn_mfma_f32_16x16x32_bf16(a, bv, acc[nt], 0, 0, 0);
    }
  }
  // GEMM3 partials over this wave's 64 cols
  float ps0=0.f, ps1=0.f, ps2=0.f, ps3=0.f;
  #pragma unroll
  for (int nt = 0; nt < 4; ++nt) {
    const int col = nh * 64 + nt * 16 + l15;
    const float bv = b1[col], wvv = W2[col];
    ps0 += fmaxf(acc[nt][0] + bv, 0.f) * wvv;
    ps1 += fmaxf(acc[nt][1] + bv, 0.f) * wvv;
    ps2 += fmaxf(acc[nt][2] + bv, 0.f) * wvv;
    ps3 += fmaxf(acc[nt][3] + bv, 0.f) * wvv;
  }
  #pragma unroll
  for (int m = 1; m < 16; m <<= 1) {
    ps0 += __shfl_xor(ps0, m, 64);
    ps1 += __shfl_xor(ps1, m, 64);
    ps2 += __shfl_xor(ps2, m, 64);
    ps3 += __shfl_xor(ps3, m, 64);
  }
  // lane l<16 picks e2v-partial of row (mrow+l): reg (l&3) of lanes lh=l>>2
  {
    const int srcLane = ((l15 >> 2) << 4) | l15;
    const float s0 = __shfl(ps0, srcLane, 64);
    const float s1 = __shfl(ps1, srcLane, 64);
    const float s2 = __shfl(ps2, srcLane, 64);
    const float s3 = __shfl(ps3, srcLane, 64);
    const float t01 = (l15 & 1) ? s1 : s0;
    const float t23 = (l15 & 1) ? s3 : s2;
    const float s = (l15 & 2) ? t23 : t01;
    if (l < 16) psumBuf[nh][mrow + l] = s;
  }
  __syncthreads();
  if (t < 32) {
    const float s = fmaxf(psumBuf[0][t] + psumBuf[1][t] + b2p[0], 0.f);
    out[OUT1OFF + pair * 128 + j0 + t] = s;
  }
}

extern "C" void kernel_launch(void* const* d_in, const int* in_sizes, int n_in,
                              void* d_out, int out_size, void* d_ws, size_t ws_size,
                              hipStream_t stream) {
  const float* x    = (const float*)d_in[0];   // [1024, 256]
  const float* E    = (const float*)d_in[1];   // [131072, 256]
  const float* Wn2e = (const float*)d_in[2];   // [512, 256]
  const float* bn2e = (const float*)d_in[3];   // [256]
  const float* W1   = (const float*)d_in[4];   // [256, 128]
  const float* b1   = (const float*)d_in[5];   // [128]
  const float* W2   = (const float*)d_in[6];   // [128]
  const float* b2   = (const float*)d_in[7];   // [1]
  float* out = (float*)d_out;

  float* Uw = (float*)d_ws;                    // [1024, 256] f32
  float* Yw = Uw + 262144;                     // [1024, 256] f32
  u16*  W1F = (u16*)(Yw + 262144);             // [32768] bf16, fragment-major

  hipLaunchKernelGGL(k1_prep, dim3(256), dim3(256), 0, stream,
                     x, Wn2e, bn2e, W1, Uw, Yw, W1F);
  // 4096 blocks x 256 threads: 32-row tiles, wave-contiguous streams, XCD swizzle
  hipLaunchKernelGGL(k2_fused, dim3(4096), dim3(256), 0, stream,
                     Uw, Yw, W1F, b1, W2, b2, E, out);
}